// Round 7
// baseline (326.344 us; speedup 1.0000x reference)
//
#include <hip/hip_runtime.h>
#include <hip/hip_fp16.h>

#define NUM_G 4096
#define OUT2_OFF ((size_t)NUM_G * 32 * 64)   // 8388608

typedef _Float16 half8  __attribute__((ext_vector_type(8)));
typedef _Float16 half4v __attribute__((ext_vector_type(4)));
typedef float    floatx4 __attribute__((ext_vector_type(4)));

__device__ __forceinline__ float lrelu(float v) { return v > 0.f ? v : 0.01f * v; }

// Swizzled LDS index (64-half rows, 16B-chunk XOR on row&7). Keeps any access
// that stays within an aligned 8-half chunk contiguous (half4v/half8 safe).
__device__ __forceinline__ int swz(int row, int col) {
    return row * 64 + (col ^ ((row & 7) << 3));
}

// ---------- setup: 18 blocks x 256 (verified R6) ----------
__global__ void setup_prep(const float* __restrict__ W, const float* __restrict__ att,
                           const float* __restrict__ Wec,
                           _Float16* __restrict__ vp16, _Float16* __restrict__ BT,
                           _Float16* __restrict__ BT2)
{
    const int t = threadIdx.x, b = blockIdx.x;
    if (b < 16) {
        __shared__ _Float16 T[8][256];
        const int kbase = b * 8;
        #pragma unroll
        for (int rr = 0; rr < 8; ++rr)
            T[rr][t] = (_Float16)W[(kbase + rr) * 256 + t];   // coalesced 1KB rows
        __syncthreads();
        const int d = t >> 2, h = t & 3;
        half8 v;
        #pragma unroll
        for (int kk = 0; kk < 8; ++kk) v[kk] = T[kk][h * 64 + d];
        *(half8*)(BT + d * 512 + h * 128 + kbase) = v;        // 16B store per thread
    } else if (b == 16) {
        for (int i = t; i < 1024; i += 256) {
            const int h8 = i >> 6, k = i & 63;
            float acc = 0.f;
            if (h8 < 8) {
                const int h = h8 & 3, ro = (h8 < 4) ? 0 : 64;
                const float4* wr = (const float4*)(W + (ro + k) * 256 + h * 64);
                const float4* ar = (const float4*)(att + h * 64);
                #pragma unroll
                for (int d4 = 0; d4 < 16; ++d4) {
                    float4 wv = wr[d4], av = ar[d4];
                    acc += wv.x * av.x + wv.y * av.y + wv.z * av.z + wv.w * av.w;
                }
            }
            vp16[i] = (_Float16)acc;
        }
    } else {
        __shared__ _Float16 T2[64][65];
        #pragma unroll
        for (int j = 0; j < 16; ++j) {
            const int idx = j * 256 + t;
            T2[idx >> 6][idx & 63] = (_Float16)Wec[idx];      // coalesced reads
        }
        __syncthreads();
        #pragma unroll
        for (int j = 0; j < 16; ++j) {
            const int idx = j * 256 + t;
            BT2[idx] = T2[idx & 63][idx >> 6];
        }
    }
}

// ---------- fused main: one block (4 waves) per TWO graphs ----------
// 2-graph ILP: every per-wave dependency chain has two independent instances,
// barriers amortize over 2 graphs, BT/BT2 fragments loaded once for both.
__global__ __launch_bounds__(256, 2) void fused_main(
    const float* __restrict__ x, const float* __restrict__ einf,
    const float* __restrict__ bias, const float* __restrict__ bec,
    const _Float16* __restrict__ vp16, const _Float16* __restrict__ BT,
    const _Float16* __restrict__ BT2,
    float* __restrict__ out, float* __restrict__ out2)
{
    __shared__ __align__(16) _Float16 R[2][128 * 64];   // swizzled: 0-31 x, 32-124 einf, 125-127 zero
    __shared__ __align__(16) _Float16 A2[2][64 * 64];   // swizzled: GEMM2 A matrix
    __shared__ __align__(16) float    sal[2][128 * 9];  // alpha pre-activations (f32)
    __shared__ __align__(16) _Float16 al4h[2][96 * 4];  // softmax weights (f16)
    __shared__ __align__(16) _Float16 virt[2][512];     // virtual-node A' row

    const int t = threadIdx.x;
    const int g0 = blockIdx.x * 2;
    const int lane = t & 63;
    const int w = t >> 6;                 // wave 0..3
    const int m16 = lane & 15, q = lane >> 4;

    // ---- P0: stage x, einf -> fp16 LDS rows (swizzled) for both graphs ----
    #pragma unroll
    for (int gi = 0; gi < 2; ++gi) {
        const float4* xg4 = (const float4*)(x + (size_t)(g0 + gi) * 2048);
        for (int i = t; i < 512; i += 256) {
            float4 v = xg4[i];
            half4v h4 = {(_Float16)v.x, (_Float16)v.y, (_Float16)v.z, (_Float16)v.w};
            *(half4v*)(R[gi] + swz(i >> 4, (i & 15) * 4)) = h4;
        }
        const float4* eg4 = (const float4*)(einf + (size_t)(g0 + gi) * 5952);
        for (int i = t; i < 1488; i += 256) {
            float4 v = eg4[i];
            half4v h4 = {(_Float16)v.x, (_Float16)v.y, (_Float16)v.z, (_Float16)v.w};
            *(half4v*)(R[gi] + swz(32 + (i >> 4), (i & 15) * 4)) = h4;
        }
        if (t < 24) {                     // rows 125-127 zero (whole rows -> swizzle-safe)
            half8 z = {0, 0, 0, 0, 0, 0, 0, 0};
            *(half8*)(R[gi] + 125 * 64 + t * 8) = z;
        }
    }
    // vp16 B-fragments for alpha MFMA (global, independent of LDS)
    half8 bF0 = *(const half8*)(vp16 + m16 * 64 + q * 8);
    half8 bF1 = *(const half8*)(vp16 + m16 * 64 + 32 + q * 8);
    __syncthreads();

    // ---- P1: alpha pre-activations via MFMA, both graphs ----
    #pragma unroll
    for (int gi = 0; gi < 2; ++gi) {
        #pragma unroll
        for (int j = 0; j < 2; ++j) {
            const int tile = w * 2 + j;
            const int row = tile * 16 + m16;
            half8 aF0 = *(const half8*)(R[gi] + swz(row, q * 8));
            half8 aF1 = *(const half8*)(R[gi] + swz(row, 32 + q * 8));
            floatx4 s = {0.f, 0.f, 0.f, 0.f};
            s = __builtin_amdgcn_mfma_f32_16x16x32_f16(aF0, bF0, s, 0, 0, 0);
            s = __builtin_amdgcn_mfma_f32_16x16x32_f16(aF1, bF1, s, 0, 0, 0);
            if (m16 < 8) {                // D: col=m16 (h8), row=q*4+r within tile
                #pragma unroll
                for (int r = 0; r < 4; ++r)
                    sal[gi][(tile * 16 + q * 4 + r) * 9 + m16] = s[r];
            }
        }
    }
    __syncthreads();

    // ---- P2: w0/w1 -> virtual softmax + virt row (g0/g1); w2/w3 -> node softmax + A2 (g0/g1) ----
    if (w < 2) {
        const int gi = w;
        const int i = lane;               // edge index for virtual node
        const bool act = (i < 31);
        float av[4], mx[4], wv[4];
        #pragma unroll
        for (int h = 0; h < 4; ++h)
            av[h] = act ? lrelu(sal[gi][i * 9 + h] + sal[gi][(94 + i) * 9 + 4 + h]) : -1e30f;
        #pragma unroll
        for (int h = 0; h < 4; ++h) {
            float m = av[h];
            #pragma unroll
            for (int off = 32; off > 0; off >>= 1)
                m = fmaxf(m, __shfl_xor(m, off, 64));
            mx[h] = m;
        }
        #pragma unroll
        for (int h = 0; h < 4; ++h) {
            float e = act ? __expf(av[h] - mx[h]) : 0.f;
            float s = e;
            #pragma unroll
            for (int off = 32; off > 0; off >>= 1)
                s += __shfl_xor(s, off, 64);
            wv[h] = e / (s + 1e-16f);
        }
        if (act) {
            half4v hv = {(_Float16)wv[0], (_Float16)wv[1], (_Float16)wv[2], (_Float16)wv[3]};
            *(half4v*)(al4h[gi] + (62 + i) * 4) = hv;
        }
        asm volatile("s_waitcnt lgkmcnt(0)" ::: "memory");   // in-wave LDS visibility
        __builtin_amdgcn_wave_barrier();
        half8 aV;
        #pragma unroll
        for (int j = 0; j < 8; ++j) {
            const int e = q * 8 + j;
            aV[j] = (m16 < 4 && e < 31) ? al4h[gi][(62 + e) * 4 + m16] : (_Float16)0.f;
        }
        #pragma unroll
        for (int hf = 0; hf < 2; ++hf) {
            const int base = hf ? 94 : 0; // hf0: x rows 0..30, hf1: einf self-edge rows 94..124
            #pragma unroll
            for (int nt = 0; nt < 4; ++nt) {
                half8 bV;
                #pragma unroll
                for (int j = 0; j < 8; ++j) {
                    const int e = q * 8 + j;
                    bV[j] = (e < 31) ? R[gi][swz(base + e, nt * 16 + m16)] : (_Float16)0.f;
                }
                floatx4 vc = {0.f, 0.f, 0.f, 0.f};
                vc = __builtin_amdgcn_mfma_f32_16x16x32_f16(aV, bV, vc, 0, 0, 0);
                if (q == 0) {             // rows 0-3 of D = heads
                    #pragma unroll
                    for (int r = 0; r < 4; ++r)
                        virt[gi][r * 128 + hf * 64 + nt * 16 + m16] = (_Float16)vc[r];
                }
            }
        }
    } else {
        const int gi = w - 2;
        // node softmax: 31 nodes x 4 heads = 124 items on 64 lanes
        #pragma unroll
        for (int rep = 0; rep < 2; ++rep) {
            const int item = lane * 2 + rep;
            if (item < 124) {
                const int n = item >> 2, h = item & 3;
                const int s1 = (n + 30) % 31, s2 = (n + 1) % 31;
                const int e1 = 2 * s1, e2 = 2 * n + 1;
                const float a1 = lrelu(sal[gi][s1 * 9 + h] + sal[gi][(32 + e1) * 9 + 4 + h]);
                const float a2 = lrelu(sal[gi][s2 * 9 + h] + sal[gi][(32 + e2) * 9 + 4 + h]);
                const float m = fmaxf(a1, a2);
                const float x1 = __expf(a1 - m), x2 = __expf(a2 - m);
                const float inv = 1.f / (x1 + x2 + 1e-16f);
                al4h[gi][e1 * 4 + h] = (_Float16)(x1 * inv);
                al4h[gi][e2 * 4 + h] = (_Float16)(x2 * inv);
            }
        }
        // A2 rows 0-61: temp (3-term) / 0.5*eisum
        for (int idx = lane; idx < 992; idx += 64) {
            const int r = idx >> 4, c = (idx & 15) * 4;
            half4v v;
            if (r < 31) {
                const int ra = 2 * ((r + 30) % 31), rb = 2 * r + 1, rc = 2 * ((r + 1) % 31) + 1;
                v = *(const half4v*)(R[gi] + swz(32 + ra, c)) + *(const half4v*)(R[gi] + swz(32 + rb, c))
                  + *(const half4v*)(R[gi] + swz(32 + rc, c));
            } else {
                const int jj = r - 31;
                const int ra = 2 * ((jj + 30) % 31), rb = 2 * jj + 1;
                v = (*(const half4v*)(R[gi] + swz(32 + ra, c)) + *(const half4v*)(R[gi] + swz(32 + rb, c)))
                    * (_Float16)0.5f;
            }
            *(half4v*)(A2[gi] + swz(r, c)) = v;
        }
        // emean row 62 (one col per lane) + zero row 63
        {
            const int c = lane;
            float s = 0.f;
            for (int i = 0; i < 31; ++i) s += (float)R[gi][swz(94 + i, c)];
            A2[gi][swz(62, c)] = (_Float16)(s * (1.f / 31.f));
            A2[gi][swz(63, c)] = (_Float16)0.f;
        }
    }
    __syncthreads();

    const int co = w * 16 + m16;
    // GEMM2 B fragments (global, L2-resident), shared across both graphs
    half8 b2a = *(const half8*)(BT2 + co * 64 + q * 8);
    half8 b2b = *(const half8*)(BT2 + co * 64 + 32 + q * 8);

    // ---- P4a: GEMM1, head-reuse + B-reuse across graphs ----
    {
        const int n1c = (16 + m16 < 31) ? 16 + m16 : 30;
        const int s1_0 = (m16 + 30) % 31, s2_0 = (m16 + 1) % 31;
        const int e1_0 = 2 * s1_0, e2_0 = 2 * m16 + 1;
        const int s1_1 = (n1c + 30) % 31, s2_1 = (n1c + 1) % 31;
        const int e1_1 = 2 * s1_1, e2_1 = 2 * n1c + 1;
        half4v a1_0[2], a2_0[2], a1_1[2], a2_1[2];
        #pragma unroll
        for (int gi = 0; gi < 2; ++gi) {
            a1_0[gi] = *(const half4v*)(al4h[gi] + e1_0 * 4);
            a2_0[gi] = *(const half4v*)(al4h[gi] + e2_0 * 4);
            a1_1[gi] = *(const half4v*)(al4h[gi] + e1_1 * 4);
            a2_1[gi] = *(const half4v*)(al4h[gi] + e2_1 * 4);
        }
        floatx4 z = {0.f, 0.f, 0.f, 0.f};
        floatx4 acc0[2] = {z, z}, acc1[2] = {z, z};
        #pragma unroll
        for (int hf = 0; hf < 2; ++hf) {
            const int rA0 = hf ? 32 + e1_0 : s1_0, rB0 = hf ? 32 + e2_0 : s2_0;
            const int rA1 = hf ? 32 + e1_1 : s1_1, rB1 = hf ? 32 + e2_1 : s2_1;
            #pragma unroll
            for (int kc = 0; kc < 2; ++kc) {
                const int k0 = kc * 32 + q * 8;
                half8 x1[2], x2[2], y1[2], y2[2];
                #pragma unroll
                for (int gi = 0; gi < 2; ++gi) {
                    x1[gi] = *(const half8*)(R[gi] + swz(rA0, k0));
                    x2[gi] = *(const half8*)(R[gi] + swz(rB0, k0));
                    y1[gi] = *(const half8*)(R[gi] + swz(rA1, k0));
                    y2[gi] = *(const half8*)(R[gi] + swz(rB1, k0));
                }
                #pragma unroll
                for (int h = 0; h < 4; ++h) {
                    half8 b = *(const half8*)(BT + co * 512 + h * 128 + hf * 64 + k0);
                    #pragma unroll
                    for (int gi = 0; gi < 2; ++gi) {
                        half8 af0 = x1[gi] * a1_0[gi][h] + x2[gi] * a2_0[gi][h];
                        acc0[gi] = __builtin_amdgcn_mfma_f32_16x16x32_f16(af0, b, acc0[gi], 0, 0, 0);
                        half8 af1 = y1[gi] * a1_1[gi][h] + y2[gi] * a2_1[gi][h];
                        half8 vv = *(const half8*)(virt[gi] + h * 128 + hf * 64 + k0);
                        af1 = (m16 == 15) ? vv : af1;
                        acc1[gi] = __builtin_amdgcn_mfma_f32_16x16x32_f16(af1, b, acc1[gi], 0, 0, 0);
                    }
                }
            }
        }
        const float bv = bias[co];
        #pragma unroll
        for (int gi = 0; gi < 2; ++gi) {
            float* og = out + (size_t)(g0 + gi) * 2048;
            #pragma unroll
            for (int r = 0; r < 4; ++r) {
                og[(q * 4 + r) * 64 + co]        = 0.25f * acc0[gi][r] + bv;
                og[(16 + q * 4 + r) * 64 + co]   = 0.25f * acc1[gi][r] + bv;
            }
        }
    }

    // ---- P4b: GEMM2 for both graphs (A2 ready since P2; B shared) ----
    {
        floatx4 z = {0.f, 0.f, 0.f, 0.f};
        floatx4 acc2[2][4];
        #pragma unroll
        for (int gi = 0; gi < 2; ++gi)
            #pragma unroll
            for (int mt = 0; mt < 4; ++mt) acc2[gi][mt] = z;
        #pragma unroll
        for (int kk = 0; kk < 2; ++kk) {
            half8 b = kk ? b2b : b2a;
            #pragma unroll
            for (int gi = 0; gi < 2; ++gi) {
                #pragma unroll
                for (int mt = 0; mt < 4; ++mt) {
                    half8 a = *(const half8*)(A2[gi] + swz(mt * 16 + m16, kk * 32 + q * 8));
                    acc2[gi][mt] = __builtin_amdgcn_mfma_f32_16x16x32_f16(a, b, acc2[gi][mt], 0, 0, 0);
                }
            }
        }
        const float bv2 = bec[co];
        #pragma unroll
        for (int gi = 0; gi < 2; ++gi) {
            float* o2 = out2 + (size_t)(g0 + gi) * 8000;   // 125*64
            #pragma unroll
            for (int mt = 0; mt < 4; ++mt) {
                #pragma unroll
                for (int r = 0; r < 4; ++r) {
                    const int row = mt * 16 + q * 4 + r;
                    if (row >= 63) continue;
                    const float v = lrelu(acc2[gi][mt][r] + bv2);
                    if (row < 31) {
                        o2[(2 * row) * 64 + co]     = v;
                        o2[(2 * row + 1) * 64 + co] = v;
                    } else if (row < 62) {
                        o2[(62 + row - 31) * 64 + co] = v;
                        o2[(94 + row - 31) * 64 + co] = v;
                    } else {
                        o2[93 * 64 + co] = v;
                    }
                }
            }
        }
    }
}

extern "C" void kernel_launch(void* const* d_in, const int* in_sizes, int n_in,
                              void* d_out, int out_size, void* d_ws, size_t ws_size,
                              hipStream_t stream) {
    const float* x    = (const float*)d_in[0];
    const float* einf = (const float*)d_in[2];
    const float* W    = (const float*)d_in[5];
    const float* att  = (const float*)d_in[6];
    const float* bias = (const float*)d_in[7];
    const float* Wec  = (const float*)d_in[8];
    const float* bec  = (const float*)d_in[9];
    float* out  = (float*)d_out;
    float* out2 = out + OUT2_OFF;

    _Float16* vp16 = (_Float16*)d_ws;                         // 1024 halves (2 KB)
    _Float16* BT   = (_Float16*)((char*)d_ws + 2048);         // 64x512 halves
    _Float16* BT2  = (_Float16*)((char*)d_ws + 2048 + 65536); // 64x64 halves

    setup_prep<<<18, 256, 0, stream>>>(W, att, Wec, vp16, BT, BT2);
    fused_main<<<NUM_G / 2, 256, 0, stream>>>(x, einf, bias, bec, vp16, BT, BT2, out, out2);
}

// Round 8
// 315.598 us; speedup vs baseline: 1.0340x; 1.0340x over previous
//
#include <hip/hip_runtime.h>
#include <hip/hip_fp16.h>

#define NUM_G 4096
#define OUT2_OFF ((size_t)NUM_G * 32 * 64)   // 8388608

typedef _Float16 half8  __attribute__((ext_vector_type(8)));
typedef _Float16 half4v __attribute__((ext_vector_type(4)));
typedef float    floatx4 __attribute__((ext_vector_type(4)));

__device__ __forceinline__ float lrelu(float v) { return v > 0.f ? v : 0.01f * v; }

// Swizzled LDS index (64-half rows, 16B-chunk XOR on row&7). Keeps any access
// that stays within an aligned 8-half chunk contiguous (half4v/half8 safe).
__device__ __forceinline__ int swz(int row, int col) {
    return row * 64 + (col ^ ((row & 7) << 3));
}

// ---------- setup: 18 blocks x 256 (verified R6) ----------
__global__ void setup_prep(const float* __restrict__ W, const float* __restrict__ att,
                           const float* __restrict__ Wec,
                           _Float16* __restrict__ vp16, _Float16* __restrict__ BT,
                           _Float16* __restrict__ BT2)
{
    const int t = threadIdx.x, b = blockIdx.x;
    if (b < 16) {
        __shared__ _Float16 T[8][256];
        const int kbase = b * 8;
        #pragma unroll
        for (int rr = 0; rr < 8; ++rr)
            T[rr][t] = (_Float16)W[(kbase + rr) * 256 + t];   // coalesced 1KB rows
        __syncthreads();
        const int d = t >> 2, h = t & 3;
        half8 v;
        #pragma unroll
        for (int kk = 0; kk < 8; ++kk) v[kk] = T[kk][h * 64 + d];
        *(half8*)(BT + d * 512 + h * 128 + kbase) = v;        // 16B store per thread
    } else if (b == 16) {
        for (int i = t; i < 1024; i += 256) {
            const int h8 = i >> 6, k = i & 63;
            float acc = 0.f;
            if (h8 < 8) {
                const int h = h8 & 3, ro = (h8 < 4) ? 0 : 64;
                const float4* wr = (const float4*)(W + (ro + k) * 256 + h * 64);
                const float4* ar = (const float4*)(att + h * 64);
                #pragma unroll
                for (int d4 = 0; d4 < 16; ++d4) {
                    float4 wv = wr[d4], av = ar[d4];
                    acc += wv.x * av.x + wv.y * av.y + wv.z * av.z + wv.w * av.w;
                }
            }
            vp16[i] = (_Float16)acc;
        }
    } else {
        __shared__ _Float16 T2[64][65];
        #pragma unroll
        for (int j = 0; j < 16; ++j) {
            const int idx = j * 256 + t;
            T2[idx >> 6][idx & 63] = (_Float16)Wec[idx];      // coalesced reads
        }
        __syncthreads();
        #pragma unroll
        for (int j = 0; j < 16; ++j) {
            const int idx = j * 256 + t;
            BT2[idx] = T2[idx & 63][idx >> 6];
        }
    }
}

// ---------- fused main: one block (4 waves) per TWO graphs, 3 blocks/CU ----------
// A2 buffer eliminated: GEMM2 A-fragments are register-fused 3-row combos of R.
// R row 127 carries the emean row; rows 125/126 stay zero (dummy operands).
__global__ __launch_bounds__(256, 3) void fused_main(
    const float* __restrict__ x, const float* __restrict__ einf,
    const float* __restrict__ bias, const float* __restrict__ bec,
    const _Float16* __restrict__ vp16, const _Float16* __restrict__ BT,
    const _Float16* __restrict__ BT2,
    float* __restrict__ out, float* __restrict__ out2)
{
    __shared__ __align__(16) _Float16 R[2][128 * 64];   // swizzled: 0-31 x, 32-124 einf, 125-126 zero, 127 emean
    __shared__ __align__(16) float    sal[2][128 * 9];  // alpha pre-activations (f32)
    __shared__ __align__(16) _Float16 al4h[2][96 * 4];  // softmax weights (f16)
    __shared__ __align__(16) _Float16 virt[2][512];     // virtual-node A' row

    const int t = threadIdx.x;
    const int g0 = blockIdx.x * 2;
    const int lane = t & 63;
    const int w = t >> 6;                 // wave 0..3
    const int m16 = lane & 15, q = lane >> 4;

    // ---- P0: stage x, einf -> fp16 LDS rows (swizzled) for both graphs ----
    #pragma unroll
    for (int gi = 0; gi < 2; ++gi) {
        const float4* xg4 = (const float4*)(x + (size_t)(g0 + gi) * 2048);
        for (int i = t; i < 512; i += 256) {
            float4 v = xg4[i];
            half4v h4 = {(_Float16)v.x, (_Float16)v.y, (_Float16)v.z, (_Float16)v.w};
            *(half4v*)(R[gi] + swz(i >> 4, (i & 15) * 4)) = h4;
        }
        const float4* eg4 = (const float4*)(einf + (size_t)(g0 + gi) * 5952);
        for (int i = t; i < 1488; i += 256) {
            float4 v = eg4[i];
            half4v h4 = {(_Float16)v.x, (_Float16)v.y, (_Float16)v.z, (_Float16)v.w};
            *(half4v*)(R[gi] + swz(32 + (i >> 4), (i & 15) * 4)) = h4;
        }
        if (t < 24) {                     // rows 125-127 zero (whole rows -> swizzle-safe)
            half8 z = {0, 0, 0, 0, 0, 0, 0, 0};
            *(half8*)(R[gi] + 125 * 64 + t * 8) = z;
        }
    }
    // vp16 B-fragments for alpha MFMA (global, independent of LDS)
    half8 bF0 = *(const half8*)(vp16 + m16 * 64 + q * 8);
    half8 bF1 = *(const half8*)(vp16 + m16 * 64 + 32 + q * 8);
    __syncthreads();

    // ---- P1: alpha pre-activations via MFMA, both graphs ----
    #pragma unroll
    for (int gi = 0; gi < 2; ++gi) {
        #pragma unroll
        for (int j = 0; j < 2; ++j) {
            const int tile = w * 2 + j;
            const int row = tile * 16 + m16;
            half8 aF0 = *(const half8*)(R[gi] + swz(row, q * 8));
            half8 aF1 = *(const half8*)(R[gi] + swz(row, 32 + q * 8));
            floatx4 s = {0.f, 0.f, 0.f, 0.f};
            s = __builtin_amdgcn_mfma_f32_16x16x32_f16(aF0, bF0, s, 0, 0, 0);
            s = __builtin_amdgcn_mfma_f32_16x16x32_f16(aF1, bF1, s, 0, 0, 0);
            if (m16 < 8) {                // D: col=m16 (h8), row=q*4+r within tile
                #pragma unroll
                for (int r = 0; r < 4; ++r)
                    sal[gi][(tile * 16 + q * 4 + r) * 9 + m16] = s[r];
            }
        }
    }
    __syncthreads();

    // ---- P2: w0/w1 -> virtual softmax + virt row (g0/g1); w2/w3 -> node softmax + emean (g0/g1) ----
    if (w < 2) {
        const int gi = w;
        const int i = lane;               // edge index for virtual node
        const bool act = (i < 31);
        float av[4], mx[4], wv[4];
        #pragma unroll
        for (int h = 0; h < 4; ++h)
            av[h] = act ? lrelu(sal[gi][i * 9 + h] + sal[gi][(94 + i) * 9 + 4 + h]) : -1e30f;
        #pragma unroll
        for (int h = 0; h < 4; ++h) {
            float m = av[h];
            #pragma unroll
            for (int off = 32; off > 0; off >>= 1)
                m = fmaxf(m, __shfl_xor(m, off, 64));
            mx[h] = m;
        }
        #pragma unroll
        for (int h = 0; h < 4; ++h) {
            float e = act ? __expf(av[h] - mx[h]) : 0.f;
            float s = e;
            #pragma unroll
            for (int off = 32; off > 0; off >>= 1)
                s += __shfl_xor(s, off, 64);
            wv[h] = e / (s + 1e-16f);
        }
        if (act) {
            half4v hv = {(_Float16)wv[0], (_Float16)wv[1], (_Float16)wv[2], (_Float16)wv[3]};
            *(half4v*)(al4h[gi] + (62 + i) * 4) = hv;
        }
        asm volatile("s_waitcnt lgkmcnt(0)" ::: "memory");   // in-wave LDS visibility
        __builtin_amdgcn_wave_barrier();
        half8 aV;
        #pragma unroll
        for (int j = 0; j < 8; ++j) {
            const int e = q * 8 + j;
            aV[j] = (m16 < 4 && e < 31) ? al4h[gi][(62 + e) * 4 + m16] : (_Float16)0.f;
        }
        #pragma unroll
        for (int hf = 0; hf < 2; ++hf) {
            const int base = hf ? 94 : 0; // hf0: x rows 0..30, hf1: einf self-edge rows 94..124
            #pragma unroll
            for (int nt = 0; nt < 4; ++nt) {
                half8 bV;
                #pragma unroll
                for (int j = 0; j < 8; ++j) {
                    const int e = q * 8 + j;
                    bV[j] = (e < 31) ? R[gi][swz(base + e, nt * 16 + m16)] : (_Float16)0.f;
                }
                floatx4 vc = {0.f, 0.f, 0.f, 0.f};
                vc = __builtin_amdgcn_mfma_f32_16x16x32_f16(aV, bV, vc, 0, 0, 0);
                if (q == 0) {             // rows 0-3 of D = heads
                    #pragma unroll
                    for (int r = 0; r < 4; ++r)
                        virt[gi][r * 128 + hf * 64 + nt * 16 + m16] = (_Float16)vc[r];
                }
            }
        }
    } else {
        const int gi = w - 2;
        // node softmax: 31 nodes x 4 heads = 124 items on 64 lanes
        #pragma unroll
        for (int rep = 0; rep < 2; ++rep) {
            const int item = lane * 2 + rep;
            if (item < 124) {
                const int n = item >> 2, h = item & 3;
                const int s1 = (n + 30) % 31, s2 = (n + 1) % 31;
                const int e1 = 2 * s1, e2 = 2 * n + 1;
                const float a1 = lrelu(sal[gi][s1 * 9 + h] + sal[gi][(32 + e1) * 9 + 4 + h]);
                const float a2 = lrelu(sal[gi][s2 * 9 + h] + sal[gi][(32 + e2) * 9 + 4 + h]);
                const float m = fmaxf(a1, a2);
                const float x1 = __expf(a1 - m), x2 = __expf(a2 - m);
                const float inv = 1.f / (x1 + x2 + 1e-16f);
                al4h[gi][e1 * 4 + h] = (_Float16)(x1 * inv);
                al4h[gi][e2 * 4 + h] = (_Float16)(x2 * inv);
            }
        }
        // emean row -> R[gi] row 127 (swizzled scalar writes)
        {
            const int c = lane;
            float s = 0.f;
            for (int i = 0; i < 31; ++i) s += (float)R[gi][swz(94 + i, c)];
            R[gi][swz(127, c)] = (_Float16)(s * (1.f / 31.f));
        }
    }
    __syncthreads();

    const int co = w * 16 + m16;
    // GEMM2 B fragments (global, L2-resident), shared across both graphs
    half8 b2a = *(const half8*)(BT2 + co * 64 + q * 8);
    half8 b2b = *(const half8*)(BT2 + co * 64 + 32 + q * 8);

    // ---- P4a: GEMM1, head-reuse + B-reuse across graphs ----
    {
        const int n1c = (16 + m16 < 31) ? 16 + m16 : 30;
        const int s1_0 = (m16 + 30) % 31, s2_0 = (m16 + 1) % 31;
        const int e1_0 = 2 * s1_0, e2_0 = 2 * m16 + 1;
        const int s1_1 = (n1c + 30) % 31, s2_1 = (n1c + 1) % 31;
        const int e1_1 = 2 * s1_1, e2_1 = 2 * n1c + 1;
        half4v a1_0[2], a2_0[2], a1_1[2], a2_1[2];
        #pragma unroll
        for (int gi = 0; gi < 2; ++gi) {
            a1_0[gi] = *(const half4v*)(al4h[gi] + e1_0 * 4);
            a2_0[gi] = *(const half4v*)(al4h[gi] + e2_0 * 4);
            a1_1[gi] = *(const half4v*)(al4h[gi] + e1_1 * 4);
            a2_1[gi] = *(const half4v*)(al4h[gi] + e2_1 * 4);
        }
        floatx4 z = {0.f, 0.f, 0.f, 0.f};
        floatx4 acc0[2] = {z, z}, acc1[2] = {z, z};
        #pragma unroll
        for (int hf = 0; hf < 2; ++hf) {
            const int rA0 = hf ? 32 + e1_0 : s1_0, rB0 = hf ? 32 + e2_0 : s2_0;
            const int rA1 = hf ? 32 + e1_1 : s1_1, rB1 = hf ? 32 + e2_1 : s2_1;
            #pragma unroll
            for (int kc = 0; kc < 2; ++kc) {
                const int k0 = kc * 32 + q * 8;
                half8 x1[2], x2[2], y1[2], y2[2];
                #pragma unroll
                for (int gi = 0; gi < 2; ++gi) {
                    x1[gi] = *(const half8*)(R[gi] + swz(rA0, k0));
                    x2[gi] = *(const half8*)(R[gi] + swz(rB0, k0));
                    y1[gi] = *(const half8*)(R[gi] + swz(rA1, k0));
                    y2[gi] = *(const half8*)(R[gi] + swz(rB1, k0));
                }
                #pragma unroll
                for (int h = 0; h < 4; ++h) {
                    half8 b = *(const half8*)(BT + co * 512 + h * 128 + hf * 64 + k0);
                    #pragma unroll
                    for (int gi = 0; gi < 2; ++gi) {
                        half8 af0 = x1[gi] * a1_0[gi][h] + x2[gi] * a2_0[gi][h];
                        acc0[gi] = __builtin_amdgcn_mfma_f32_16x16x32_f16(af0, b, acc0[gi], 0, 0, 0);
                        half8 af1 = y1[gi] * a1_1[gi][h] + y2[gi] * a2_1[gi][h];
                        half8 vv = *(const half8*)(virt[gi] + h * 128 + hf * 64 + k0);
                        af1 = (m16 == 15) ? vv : af1;
                        acc1[gi] = __builtin_amdgcn_mfma_f32_16x16x32_f16(af1, b, acc1[gi], 0, 0, 0);
                    }
                }
            }
        }
        const float bv = bias[co];
        #pragma unroll
        for (int gi = 0; gi < 2; ++gi) {
            float* og = out + (size_t)(g0 + gi) * 2048;
            #pragma unroll
            for (int r = 0; r < 4; ++r) {
                og[(q * 4 + r) * 64 + co]        = 0.25f * acc0[gi][r] + bv;
                og[(16 + q * 4 + r) * 64 + co]   = 0.25f * acc1[gi][r] + bv;
            }
        }
    }

    // ---- P4b: GEMM2 with register-fused A rows (no A2 buffer) ----
    {
        floatx4 z = {0.f, 0.f, 0.f, 0.f};
        floatx4 acc2[2][4];
        #pragma unroll
        for (int gi = 0; gi < 2; ++gi)
            #pragma unroll
            for (int mt = 0; mt < 4; ++mt) acc2[gi][mt] = z;
        #pragma unroll
        for (int mt = 0; mt < 4; ++mt) {
            const int r_ = mt * 16 + m16;
            int i1, i2, i3;
            _Float16 sc;
            if (r_ < 31) {                 // temp: 3-term sum, weight 1
                const int prev = (r_ == 0) ? 30 : r_ - 1;
                const int next = (r_ == 30) ? 0 : r_ + 1;
                i1 = 32 + 2 * prev;
                i2 = 32 + 2 * r_ + 1;
                i3 = 32 + 2 * next + 1;
                sc = (_Float16)1.f;
            } else if (r_ < 62) {          // 0.5*eisum: 2-term sum + zero row
                const int jj = r_ - 31;
                const int prevj = (jj == 0) ? 30 : jj - 1;
                i1 = 32 + 2 * prevj;
                i2 = 32 + 2 * jj + 1;
                i3 = 125;                  // zero row
                sc = (_Float16)0.5f;
            } else if (r_ == 62) {         // emean row
                i1 = 127; i2 = 125; i3 = 126;
                sc = (_Float16)1.f;
            } else {                       // row 63: zero
                i1 = 125; i2 = 126; i3 = 125;
                sc = (_Float16)1.f;
            }
            #pragma unroll
            for (int kk = 0; kk < 2; ++kk) {
                const int k0 = kk * 32 + q * 8;
                half8 b = kk ? b2b : b2a;
                #pragma unroll
                for (int gi = 0; gi < 2; ++gi) {
                    half8 a = (*(const half8*)(R[gi] + swz(i1, k0))
                             + *(const half8*)(R[gi] + swz(i2, k0))
                             + *(const half8*)(R[gi] + swz(i3, k0))) * sc;
                    acc2[gi][mt] = __builtin_amdgcn_mfma_f32_16x16x32_f16(a, b, acc2[gi][mt], 0, 0, 0);
                }
            }
        }
        const float bv2 = bec[co];
        #pragma unroll
        for (int gi = 0; gi < 2; ++gi) {
            float* o2 = out2 + (size_t)(g0 + gi) * 8000;   // 125*64
            #pragma unroll
            for (int mt = 0; mt < 4; ++mt) {
                #pragma unroll
                for (int r = 0; r < 4; ++r) {
                    const int row = mt * 16 + q * 4 + r;
                    if (row >= 63) continue;
                    const float v = lrelu(acc2[gi][mt][r] + bv2);
                    if (row < 31) {
                        o2[(2 * row) * 64 + co]     = v;
                        o2[(2 * row + 1) * 64 + co] = v;
                    } else if (row < 62) {
                        o2[(62 + row - 31) * 64 + co] = v;
                        o2[(94 + row - 31) * 64 + co] = v;
                    } else {
                        o2[93 * 64 + co] = v;
                    }
                }
            }
        }
    }
}

extern "C" void kernel_launch(void* const* d_in, const int* in_sizes, int n_in,
                              void* d_out, int out_size, void* d_ws, size_t ws_size,
                              hipStream_t stream) {
    const float* x    = (const float*)d_in[0];
    const float* einf = (const float*)d_in[2];
    const float* W    = (const float*)d_in[5];
    const float* att  = (const float*)d_in[6];
    const float* bias = (const float*)d_in[7];
    const float* Wec  = (const float*)d_in[8];
    const float* bec  = (const float*)d_in[9];
    float* out  = (float*)d_out;
    float* out2 = out + OUT2_OFF;

    _Float16* vp16 = (_Float16*)d_ws;                         // 1024 halves (2 KB)
    _Float16* BT   = (_Float16*)((char*)d_ws + 2048);         // 64x512 halves
    _Float16* BT2  = (_Float16*)((char*)d_ws + 2048 + 65536); // 64x64 halves

    setup_prep<<<18, 256, 0, stream>>>(W, att, Wec, vp16, BT, BT2);
    fused_main<<<NUM_G / 2, 256, 0, stream>>>(x, einf, bias, bec, vp16, BT, BT2, out, out2);
}

// Round 9
// 308.665 us; speedup vs baseline: 1.0573x; 1.0225x over previous
//
#include <hip/hip_runtime.h>
#include <hip/hip_fp16.h>

#define NUM_G 4096
#define OUT2_OFF ((size_t)NUM_G * 32 * 64)   // 8388608

typedef _Float16 half8  __attribute__((ext_vector_type(8)));
typedef _Float16 half4v __attribute__((ext_vector_type(4)));
typedef float    floatx4 __attribute__((ext_vector_type(4)));

__device__ __forceinline__ float lrelu(float v) { return v > 0.f ? v : 0.01f * v; }

// Swizzled LDS index (64-half rows, 16B-chunk XOR on row&7). Keeps any access
// that stays within an aligned 8-half chunk contiguous (half4v/half8 safe).
__device__ __forceinline__ int swz(int row, int col) {
    return row * 64 + (col ^ ((row & 7) << 3));
}

// ---------- setup: 18 blocks x 256 (verified R6) ----------
__global__ void setup_prep(const float* __restrict__ W, const float* __restrict__ att,
                           const float* __restrict__ Wec,
                           _Float16* __restrict__ vp16, _Float16* __restrict__ BT,
                           _Float16* __restrict__ BT2)
{
    const int t = threadIdx.x, b = blockIdx.x;
    if (b < 16) {
        __shared__ _Float16 T[8][256];
        const int kbase = b * 8;
        #pragma unroll
        for (int rr = 0; rr < 8; ++rr)
            T[rr][t] = (_Float16)W[(kbase + rr) * 256 + t];   // coalesced 1KB rows
        __syncthreads();
        const int d = t >> 2, h = t & 3;
        half8 v;
        #pragma unroll
        for (int kk = 0; kk < 8; ++kk) v[kk] = T[kk][h * 64 + d];
        *(half8*)(BT + d * 512 + h * 128 + kbase) = v;        // 16B store per thread
    } else if (b == 16) {
        for (int i = t; i < 1024; i += 256) {
            const int h8 = i >> 6, k = i & 63;
            float acc = 0.f;
            if (h8 < 8) {
                const int h = h8 & 3, ro = (h8 < 4) ? 0 : 64;
                const float4* wr = (const float4*)(W + (ro + k) * 256 + h * 64);
                const float4* ar = (const float4*)(att + h * 64);
                #pragma unroll
                for (int d4 = 0; d4 < 16; ++d4) {
                    float4 wv = wr[d4], av = ar[d4];
                    acc += wv.x * av.x + wv.y * av.y + wv.z * av.z + wv.w * av.w;
                }
            }
            vp16[i] = (_Float16)acc;
        }
    } else {
        __shared__ _Float16 T2[64][65];
        #pragma unroll
        for (int j = 0; j < 16; ++j) {
            const int idx = j * 256 + t;
            T2[idx >> 6][idx & 63] = (_Float16)Wec[idx];      // coalesced reads
        }
        __syncthreads();
        #pragma unroll
        for (int j = 0; j < 16; ++j) {
            const int idx = j * 256 + t;
            BT2[idx] = T2[idx & 63][idx >> 6];
        }
    }
}

// ---------- fused main: one block (4 waves) per TWO graphs, 4 blocks/CU ----------
// LDS = 40960 B exactly (sal stored f16) -> 4 blocks/CU, 8 independent
// graph-chains per SIMD. A2 register-fused from R (no A2 buffer); R row 127
// carries emean, rows 125/126 zero.
__global__ __launch_bounds__(256, 4) void fused_main(
    const float* __restrict__ x, const float* __restrict__ einf,
    const float* __restrict__ bias, const float* __restrict__ bec,
    const _Float16* __restrict__ vp16, const _Float16* __restrict__ BT,
    const _Float16* __restrict__ BT2,
    float* __restrict__ out, float* __restrict__ out2)
{
    __shared__ __align__(16) _Float16 R[2][128 * 64];   // swizzled: 0-31 x, 32-124 einf, 125-126 zero, 127 emean
    __shared__ __align__(16) _Float16 sal[2][128 * 9];  // alpha pre-activations (f16, stride 9)
    __shared__ __align__(16) _Float16 al4h[2][96 * 4];  // softmax weights (f16)
    __shared__ __align__(16) _Float16 virt[2][512];     // virtual-node A' row

    const int t = threadIdx.x;
    const int g0 = blockIdx.x * 2;
    const int lane = t & 63;
    const int w = t >> 6;                 // wave 0..3
    const int m16 = lane & 15, q = lane >> 4;

    // ---- P0: stage x, einf -> fp16 LDS rows (swizzled) for both graphs ----
    #pragma unroll
    for (int gi = 0; gi < 2; ++gi) {
        const float4* xg4 = (const float4*)(x + (size_t)(g0 + gi) * 2048);
        for (int i = t; i < 512; i += 256) {
            float4 v = xg4[i];
            half4v h4 = {(_Float16)v.x, (_Float16)v.y, (_Float16)v.z, (_Float16)v.w};
            *(half4v*)(R[gi] + swz(i >> 4, (i & 15) * 4)) = h4;
        }
        const float4* eg4 = (const float4*)(einf + (size_t)(g0 + gi) * 5952);
        for (int i = t; i < 1488; i += 256) {
            float4 v = eg4[i];
            half4v h4 = {(_Float16)v.x, (_Float16)v.y, (_Float16)v.z, (_Float16)v.w};
            *(half4v*)(R[gi] + swz(32 + (i >> 4), (i & 15) * 4)) = h4;
        }
        if (t < 24) {                     // rows 125-127 zero (whole rows -> swizzle-safe)
            half8 z = {0, 0, 0, 0, 0, 0, 0, 0};
            *(half8*)(R[gi] + 125 * 64 + t * 8) = z;
        }
    }
    // vp16 B-fragments for alpha MFMA (global, independent of LDS)
    half8 bF0 = *(const half8*)(vp16 + m16 * 64 + q * 8);
    half8 bF1 = *(const half8*)(vp16 + m16 * 64 + 32 + q * 8);
    __syncthreads();

    // ---- P1: alpha pre-activations via MFMA, both graphs ----
    #pragma unroll
    for (int gi = 0; gi < 2; ++gi) {
        #pragma unroll
        for (int j = 0; j < 2; ++j) {
            const int tile = w * 2 + j;
            const int row = tile * 16 + m16;
            half8 aF0 = *(const half8*)(R[gi] + swz(row, q * 8));
            half8 aF1 = *(const half8*)(R[gi] + swz(row, 32 + q * 8));
            floatx4 s = {0.f, 0.f, 0.f, 0.f};
            s = __builtin_amdgcn_mfma_f32_16x16x32_f16(aF0, bF0, s, 0, 0, 0);
            s = __builtin_amdgcn_mfma_f32_16x16x32_f16(aF1, bF1, s, 0, 0, 0);
            if (m16 < 8) {                // D: col=m16 (h8), row=q*4+r within tile
                #pragma unroll
                for (int r = 0; r < 4; ++r)
                    sal[gi][(tile * 16 + q * 4 + r) * 9 + m16] = (_Float16)s[r];
            }
        }
    }
    __syncthreads();

    // ---- P2: w0/w1 -> virtual softmax + virt row (g0/g1); w2/w3 -> node softmax + emean (g0/g1) ----
    if (w < 2) {
        const int gi = w;
        const int i = lane;               // edge index for virtual node
        const bool act = (i < 31);
        float av[4], mx[4], wv[4];
        #pragma unroll
        for (int h = 0; h < 4; ++h)
            av[h] = act ? lrelu((float)sal[gi][i * 9 + h] + (float)sal[gi][(94 + i) * 9 + 4 + h]) : -1e30f;
        #pragma unroll
        for (int h = 0; h < 4; ++h) {
            float m = av[h];
            #pragma unroll
            for (int off = 32; off > 0; off >>= 1)
                m = fmaxf(m, __shfl_xor(m, off, 64));
            mx[h] = m;
        }
        #pragma unroll
        for (int h = 0; h < 4; ++h) {
            float e = act ? __expf(av[h] - mx[h]) : 0.f;
            float s = e;
            #pragma unroll
            for (int off = 32; off > 0; off >>= 1)
                s += __shfl_xor(s, off, 64);
            wv[h] = e / (s + 1e-16f);
        }
        if (act) {
            half4v hv = {(_Float16)wv[0], (_Float16)wv[1], (_Float16)wv[2], (_Float16)wv[3]};
            *(half4v*)(al4h[gi] + (62 + i) * 4) = hv;
        }
        asm volatile("s_waitcnt lgkmcnt(0)" ::: "memory");   // in-wave LDS visibility
        __builtin_amdgcn_wave_barrier();
        half8 aV;
        #pragma unroll
        for (int j = 0; j < 8; ++j) {
            const int e = q * 8 + j;
            aV[j] = (m16 < 4 && e < 31) ? al4h[gi][(62 + e) * 4 + m16] : (_Float16)0.f;
        }
        #pragma unroll
        for (int hf = 0; hf < 2; ++hf) {
            const int base = hf ? 94 : 0; // hf0: x rows 0..30, hf1: einf self-edge rows 94..124
            #pragma unroll
            for (int nt = 0; nt < 4; ++nt) {
                half8 bV;
                #pragma unroll
                for (int j = 0; j < 8; ++j) {
                    const int e = q * 8 + j;
                    bV[j] = (e < 31) ? R[gi][swz(base + e, nt * 16 + m16)] : (_Float16)0.f;
                }
                floatx4 vc = {0.f, 0.f, 0.f, 0.f};
                vc = __builtin_amdgcn_mfma_f32_16x16x32_f16(aV, bV, vc, 0, 0, 0);
                if (q == 0) {             // rows 0-3 of D = heads
                    #pragma unroll
                    for (int r = 0; r < 4; ++r)
                        virt[gi][r * 128 + hf * 64 + nt * 16 + m16] = (_Float16)vc[r];
                }
            }
        }
    } else {
        const int gi = w - 2;
        // node softmax: 31 nodes x 4 heads = 124 items on 64 lanes
        #pragma unroll
        for (int rep = 0; rep < 2; ++rep) {
            const int item = lane * 2 + rep;
            if (item < 124) {
                const int n = item >> 2, h = item & 3;
                const int s1 = (n + 30) % 31, s2 = (n + 1) % 31;
                const int e1 = 2 * s1, e2 = 2 * n + 1;
                const float a1 = lrelu((float)sal[gi][s1 * 9 + h] + (float)sal[gi][(32 + e1) * 9 + 4 + h]);
                const float a2 = lrelu((float)sal[gi][s2 * 9 + h] + (float)sal[gi][(32 + e2) * 9 + 4 + h]);
                const float m = fmaxf(a1, a2);
                const float x1 = __expf(a1 - m), x2 = __expf(a2 - m);
                const float inv = 1.f / (x1 + x2 + 1e-16f);
                al4h[gi][e1 * 4 + h] = (_Float16)(x1 * inv);
                al4h[gi][e2 * 4 + h] = (_Float16)(x2 * inv);
            }
        }
        // emean row -> R[gi] row 127 (swizzled scalar writes)
        {
            const int c = lane;
            float s = 0.f;
            for (int i = 0; i < 31; ++i) s += (float)R[gi][swz(94 + i, c)];
            R[gi][swz(127, c)] = (_Float16)(s * (1.f / 31.f));
        }
    }
    __syncthreads();

    const int co = w * 16 + m16;
    // GEMM2 B fragments (global, L2-resident), shared across both graphs
    half8 b2a = *(const half8*)(BT2 + co * 64 + q * 8);
    half8 b2b = *(const half8*)(BT2 + co * 64 + 32 + q * 8);

    // ---- P4a: GEMM1, head-reuse + B-reuse across graphs ----
    {
        const int n1c = (16 + m16 < 31) ? 16 + m16 : 30;
        const int s1_0 = (m16 + 30) % 31, s2_0 = (m16 + 1) % 31;
        const int e1_0 = 2 * s1_0, e2_0 = 2 * m16 + 1;
        const int s1_1 = (n1c + 30) % 31, s2_1 = (n1c + 1) % 31;
        const int e1_1 = 2 * s1_1, e2_1 = 2 * n1c + 1;
        half4v a1_0[2], a2_0[2], a1_1[2], a2_1[2];
        #pragma unroll
        for (int gi = 0; gi < 2; ++gi) {
            a1_0[gi] = *(const half4v*)(al4h[gi] + e1_0 * 4);
            a2_0[gi] = *(const half4v*)(al4h[gi] + e2_0 * 4);
            a1_1[gi] = *(const half4v*)(al4h[gi] + e1_1 * 4);
            a2_1[gi] = *(const half4v*)(al4h[gi] + e2_1 * 4);
        }
        floatx4 z = {0.f, 0.f, 0.f, 0.f};
        floatx4 acc0[2] = {z, z}, acc1[2] = {z, z};
        #pragma unroll
        for (int hf = 0; hf < 2; ++hf) {
            const int rA0 = hf ? 32 + e1_0 : s1_0, rB0 = hf ? 32 + e2_0 : s2_0;
            const int rA1 = hf ? 32 + e1_1 : s1_1, rB1 = hf ? 32 + e2_1 : s2_1;
            #pragma unroll
            for (int kc = 0; kc < 2; ++kc) {
                const int k0 = kc * 32 + q * 8;
                half8 x1[2], x2[2], y1[2], y2[2];
                #pragma unroll
                for (int gi = 0; gi < 2; ++gi) {
                    x1[gi] = *(const half8*)(R[gi] + swz(rA0, k0));
                    x2[gi] = *(const half8*)(R[gi] + swz(rB0, k0));
                    y1[gi] = *(const half8*)(R[gi] + swz(rA1, k0));
                    y2[gi] = *(const half8*)(R[gi] + swz(rB1, k0));
                }
                #pragma unroll
                for (int h = 0; h < 4; ++h) {
                    half8 b = *(const half8*)(BT + co * 512 + h * 128 + hf * 64 + k0);
                    #pragma unroll
                    for (int gi = 0; gi < 2; ++gi) {
                        half8 af0 = x1[gi] * a1_0[gi][h] + x2[gi] * a2_0[gi][h];
                        acc0[gi] = __builtin_amdgcn_mfma_f32_16x16x32_f16(af0, b, acc0[gi], 0, 0, 0);
                        half8 af1 = y1[gi] * a1_1[gi][h] + y2[gi] * a2_1[gi][h];
                        half8 vv = *(const half8*)(virt[gi] + h * 128 + hf * 64 + k0);
                        af1 = (m16 == 15) ? vv : af1;
                        acc1[gi] = __builtin_amdgcn_mfma_f32_16x16x32_f16(af1, b, acc1[gi], 0, 0, 0);
                    }
                }
            }
        }
        const float bv = bias[co];
        #pragma unroll
        for (int gi = 0; gi < 2; ++gi) {
            float* og = out + (size_t)(g0 + gi) * 2048;
            #pragma unroll
            for (int r = 0; r < 4; ++r) {
                og[(q * 4 + r) * 64 + co]        = 0.25f * acc0[gi][r] + bv;
                og[(16 + q * 4 + r) * 64 + co]   = 0.25f * acc1[gi][r] + bv;
            }
        }
    }

    // ---- P4b: GEMM2 with register-fused A rows (no A2 buffer) ----
    {
        floatx4 z = {0.f, 0.f, 0.f, 0.f};
        floatx4 acc2[2][4];
        #pragma unroll
        for (int gi = 0; gi < 2; ++gi)
            #pragma unroll
            for (int mt = 0; mt < 4; ++mt) acc2[gi][mt] = z;
        #pragma unroll
        for (int mt = 0; mt < 4; ++mt) {
            const int r_ = mt * 16 + m16;
            int i1, i2, i3;
            _Float16 sc;
            if (r_ < 31) {                 // temp: 3-term sum, weight 1
                const int prev = (r_ == 0) ? 30 : r_ - 1;
                const int next = (r_ == 30) ? 0 : r_ + 1;
                i1 = 32 + 2 * prev;
                i2 = 32 + 2 * r_ + 1;
                i3 = 32 + 2 * next + 1;
                sc = (_Float16)1.f;
            } else if (r_ < 62) {          // 0.5*eisum: 2-term sum + zero row
                const int jj = r_ - 31;
                const int prevj = (jj == 0) ? 30 : jj - 1;
                i1 = 32 + 2 * prevj;
                i2 = 32 + 2 * jj + 1;
                i3 = 125;                  // zero row
                sc = (_Float16)0.5f;
            } else if (r_ == 62) {         // emean row
                i1 = 127; i2 = 125; i3 = 126;
                sc = (_Float16)1.f;
            } else {                       // row 63: zero
                i1 = 125; i2 = 126; i3 = 125;
                sc = (_Float16)1.f;
            }
            #pragma unroll
            for (int kk = 0; kk < 2; ++kk) {
                const int k0 = kk * 32 + q * 8;
                half8 b = kk ? b2b : b2a;
                #pragma unroll
                for (int gi = 0; gi < 2; ++gi) {
                    half8 a = (*(const half8*)(R[gi] + swz(i1, k0))
                             + *(const half8*)(R[gi] + swz(i2, k0))
                             + *(const half8*)(R[gi] + swz(i3, k0))) * sc;
                    acc2[gi][mt] = __builtin_amdgcn_mfma_f32_16x16x32_f16(a, b, acc2[gi][mt], 0, 0, 0);
                }
            }
        }
        const float bv2 = bec[co];
        #pragma unroll
        for (int gi = 0; gi < 2; ++gi) {
            float* o2 = out2 + (size_t)(g0 + gi) * 8000;   // 125*64
            #pragma unroll
            for (int mt = 0; mt < 4; ++mt) {
                #pragma unroll
                for (int r = 0; r < 4; ++r) {
                    const int row = mt * 16 + q * 4 + r;
                    if (row >= 63) continue;
                    const float v = lrelu(acc2[gi][mt][r] + bv2);
                    if (row < 31) {
                        o2[(2 * row) * 64 + co]     = v;
                        o2[(2 * row + 1) * 64 + co] = v;
                    } else if (row < 62) {
                        o2[(62 + row - 31) * 64 + co] = v;
                        o2[(94 + row - 31) * 64 + co] = v;
                    } else {
                        o2[93 * 64 + co] = v;
                    }
                }
            }
        }
    }
}

extern "C" void kernel_launch(void* const* d_in, const int* in_sizes, int n_in,
                              void* d_out, int out_size, void* d_ws, size_t ws_size,
                              hipStream_t stream) {
    const float* x    = (const float*)d_in[0];
    const float* einf = (const float*)d_in[2];
    const float* W    = (const float*)d_in[5];
    const float* att  = (const float*)d_in[6];
    const float* bias = (const float*)d_in[7];
    const float* Wec  = (const float*)d_in[8];
    const float* bec  = (const float*)d_in[9];
    float* out  = (float*)d_out;
    float* out2 = out + OUT2_OFF;

    _Float16* vp16 = (_Float16*)d_ws;                         // 1024 halves (2 KB)
    _Float16* BT   = (_Float16*)((char*)d_ws + 2048);         // 64x512 halves
    _Float16* BT2  = (_Float16*)((char*)d_ws + 2048 + 65536); // 64x64 halves

    setup_prep<<<18, 256, 0, stream>>>(W, att, Wec, vp16, BT, BT2);
    fused_main<<<NUM_G / 2, 256, 0, stream>>>(x, einf, bias, bec, vp16, BT, BT2, out, out2);
}